// Round 1
// baseline (165.467 us; speedup 1.0000x reference)
//
#include <hip/hip_runtime.h>

#define B_   8
#define L_   2048
#define DIN  256
#define DBCW 48          // dt_rank + 2*d_state
#define ROWS (B_ * L_)   // 16384
#define CHUNK 32
#define NC   (L_ / CHUNK) // 64
#define LN_EPS 1e-6f
#define LOG_EPS_F (-27.63102112f)   // ln(1e-12)

// ---------------- K1: dbc = silu(LN(inputs @ W_dbc)) ----------------
// block = 128 threads, 8 rows per block. LDS: 8 input rows + W^T.
__global__ __launch_bounds__(128) void k_dbc(const float* __restrict__ in,
                                             const float* __restrict__ W,
                                             const float* __restrict__ g1,
                                             const float* __restrict__ b1,
                                             float* __restrict__ dbc) {
    __shared__ __align__(16) float in_s[8 * 260];
    __shared__ __align__(16) float Wt[48 * 260];   // Wt[j*260+k] = W[k*48+j]
    const int t  = threadIdx.x;
    const int r0 = blockIdx.x * 8;
    for (int x = t; x < 8 * 256; x += 128) {
        int i = x >> 8, k = x & 255;
        in_s[i * 260 + k] = in[(r0 + i) * DIN + k];
    }
    for (int x = t; x < 256 * 48; x += 128) {
        int k = x / 48, j = x - k * 48;
        Wt[j * 260 + k] = W[x];
    }
    __syncthreads();

    const int rr = t >> 4;   // 0..7  (row within block)
    const int jj = t & 15;   // 0..15 (column group)
    const float4* inr = reinterpret_cast<const float4*>(&in_s[rr * 260]);

    float acc[3];
    #pragma unroll
    for (int jt = 0; jt < 3; ++jt) {
        const int j = jj + 16 * jt;
        const float4* wr = reinterpret_cast<const float4*>(&Wt[j * 260]);
        float a = 0.f;
        #pragma unroll 4
        for (int ki = 0; ki < 64; ++ki) {
            float4 x = inr[ki], w = wr[ki];
            a += x.x * w.x + x.y * w.y + x.z * w.z + x.w * w.w;
        }
        acc[jt] = a;
    }
    // LayerNorm over the 48 values of this row (held by 16 lanes x 3)
    float s = acc[0] + acc[1] + acc[2];
    float q = acc[0] * acc[0] + acc[1] * acc[1] + acc[2] * acc[2];
    #pragma unroll
    for (int m = 1; m < 16; m <<= 1) {
        s += __shfl_xor(s, m, 16);
        q += __shfl_xor(q, m, 16);
    }
    const float mean = s * (1.f / 48.f);
    const float var  = q * (1.f / 48.f) - mean * mean;
    const float rs   = rsqrtf(var + LN_EPS);
    const int r = r0 + rr;
    #pragma unroll
    for (int jt = 0; jt < 3; ++jt) {
        const int j = jj + 16 * jt;
        float y = (acc[jt] - mean) * rs * g1[j] + b1[j];
        float sil = y / (1.f + __expf(-y));       // silu
        dbc[r * DBCW + j] = sil;
    }
}

// ---------------- K2: delta = softplus(LN(delta_r @ W_dt + b_dt)) ----------------
// one block (256 threads) per row
__global__ __launch_bounds__(256) void k_delta(const float* __restrict__ dbc,
                                               const float* __restrict__ Wdt,
                                               const float* __restrict__ bdt,
                                               const float* __restrict__ g2,
                                               const float* __restrict__ b2,
                                               float* __restrict__ delta) {
    const int r = blockIdx.x;
    const int d = threadIdx.x;
    __shared__ float dr[16];
    __shared__ float red[8];
    if (d < 16) dr[d] = dbc[r * DBCW + d];
    __syncthreads();
    float pre = bdt[d];
    #pragma unroll
    for (int k = 0; k < 16; ++k) pre += dr[k] * Wdt[k * DIN + d];
    // block LN over 256
    float s = pre, q = pre * pre;
    #pragma unroll
    for (int m = 1; m < 64; m <<= 1) {
        s += __shfl_xor(s, m, 64);
        q += __shfl_xor(q, m, 64);
    }
    if ((d & 63) == 0) { red[d >> 6] = s; red[4 + (d >> 6)] = q; }
    __syncthreads();
    s = red[0] + red[1] + red[2] + red[3];
    q = red[4] + red[5] + red[6] + red[7];
    const float mean = s * (1.f / 256.f);
    const float var  = q * (1.f / 256.f) - mean * mean;
    float y = (pre - mean) * rsqrtf(var + LN_EPS) * g2[d] + b2[d];
    float sp = (y > 20.f) ? y : log1pf(__expf(y));  // softplus
    delta[r * DIN + d] = sp;
}

// ---------------- K3 (phase A): per-chunk local scan ----------------
// block = (b, chunk), thread = d. 16 n-states in registers.
__global__ __launch_bounds__(256) void k_scanA(const float* __restrict__ delta,
                                               const float* __restrict__ in,
                                               const float* __restrict__ dbc,
                                               const float* __restrict__ Alog,
                                               float* __restrict__ Ebuf,
                                               float* __restrict__ Tbuf) {
    const int bi = blockIdx.x;
    const int b = bi / NC, c = bi % NC;
    const int d = threadIdx.x;
    float An[16];
    #pragma unroll
    for (int n = 0; n < 16; ++n) An[n] = -__expf(Alog[d * 16 + n]);
    float y[16];
    #pragma unroll
    for (int n = 0; n < 16; ++n) y[n] = 0.f;
    float T = 0.f;
    const int l0 = c * CHUNK;
    for (int li = 0; li < CHUNK; ++li) {
        const int r  = b * L_ + l0 + li;
        const float dl = delta[r * DIN + d];
        const float u  = in[r * DIN + d];
        const float du = dl * u;
        const float4* Bp = reinterpret_cast<const float4*>(dbc + r * DBCW + 16);
        float Bv[16];
        #pragma unroll
        for (int i = 0; i < 4; ++i) {
            float4 v = Bp[i];
            Bv[4*i] = v.x; Bv[4*i+1] = v.y; Bv[4*i+2] = v.z; Bv[4*i+3] = v.w;
        }
        #pragma unroll
        for (int n = 0; n < 16; ++n) {
            float g = __expf(dl * An[n]);
            y[n] = g * y[n] + du * Bv[n];
        }
        T += dl;
    }
    const int idx = (b * NC + c) * 256 + d;
    float4* Ep = reinterpret_cast<float4*>(Ebuf + (size_t)idx * 16);
    #pragma unroll
    for (int i = 0; i < 4; ++i)
        Ep[i] = make_float4(y[4*i], y[4*i+1], y[4*i+2], y[4*i+3]);
    Tbuf[idx] = T;
}

// ---------------- K4 (phase B): stitch chunk carries ----------------
// thread = (b, d, n); loops over 64 chunks
__global__ __launch_bounds__(256) void k_scanB(const float* __restrict__ Alog,
                                               const float* __restrict__ Ebuf,
                                               const float* __restrict__ Tbuf,
                                               float* __restrict__ Hbuf,
                                               float* __restrict__ Rbuf) {
    const int tid = blockIdx.x * 256 + threadIdx.x;
    const int b = tid >> 12;
    const int d = (tid >> 4) & 255;
    const int n = tid & 15;
    const float An = -__expf(Alog[d * 16 + n]);
    float Ttot = 0.f;
    for (int c = 0; c < NC; ++c) Ttot += Tbuf[(b * NC + c) * 256 + d];
    float h = 0.f, P = 0.f;
    for (int c = 0; c < NC; ++c) {
        const int idx = (b * NC + c) * 256 + d;
        const float Tc = Tbuf[idx];
        Hbuf[(size_t)idx * 16 + n] = h;        // carry INTO chunk c
        const float E = Ebuf[(size_t)idx * 16 + n];
        const float G = __expf(An * Tc);       // chunk decay
        h = E + G * h;
        P += Tc;
        if (n == 0) Rbuf[idx] = Ttot - P;      // suffix delta-sum AFTER chunk c
    }
}

// ---------------- K5 (phase C): replay with carry + fade + output ----------------
__global__ __launch_bounds__(256) void k_scanC(const float* __restrict__ delta,
                                               const float* __restrict__ in,
                                               const float* __restrict__ dbc,
                                               const float* __restrict__ Alog,
                                               const float* __restrict__ Hbuf,
                                               const float* __restrict__ Tbuf,
                                               const float* __restrict__ Rbuf,
                                               const float* __restrict__ Dv,
                                               float* __restrict__ out) {
    const int bi = blockIdx.x;
    const int b = bi / NC, c = bi % NC;
    const int d = threadIdx.x;
    float An[16];
    #pragma unroll
    for (int n = 0; n < 16; ++n) An[n] = -__expf(Alog[d * 16 + n]);
    const int idx = (b * NC + c) * 256 + d;
    float y[16];
    const float4* Hp = reinterpret_cast<const float4*>(Hbuf + (size_t)idx * 16);
    #pragma unroll
    for (int i = 0; i < 4; ++i) {
        float4 v = Hp[i];
        y[4*i] = v.x; y[4*i+1] = v.y; y[4*i+2] = v.z; y[4*i+3] = v.w;
    }
    const float T  = Tbuf[idx];
    const float R  = Rbuf[idx];
    const float Dd = Dv[d];
    float Q = 0.f;
    const int l0 = c * CHUNK;
    for (int li = 0; li < CHUNK; ++li) {
        const int r  = b * L_ + l0 + li;
        const float dl = delta[r * DIN + d];
        const float u  = in[r * DIN + d];
        const float du = dl * u;
        const float4* Bp = reinterpret_cast<const float4*>(dbc + r * DBCW + 16);
        const float4* Cp = reinterpret_cast<const float4*>(dbc + r * DBCW + 32);
        float Bv[16], Cv[16];
        #pragma unroll
        for (int i = 0; i < 4; ++i) {
            float4 v = Bp[i];
            Bv[4*i] = v.x; Bv[4*i+1] = v.y; Bv[4*i+2] = v.z; Bv[4*i+3] = v.w;
            float4 w = Cp[i];
            Cv[4*i] = w.x; Cv[4*i+1] = w.y; Cv[4*i+2] = w.z; Cv[4*i+3] = w.w;
        }
        Q += dl;
        const float suf = (T - Q) + R;   // sum of delta for k > l (global)
        float o = 0.f;
        #pragma unroll
        for (int n = 0; n < 16; ++n) {
            const float g = __expf(dl * An[n]);
            y[n] = g * y[n] + du * Bv[n];
            const float e = (-An[n]) * suf + LOG_EPS_F;   // S_l + ln(eps)
            const float f = (e > 30.f) ? 0.f : 1.f / (1.f + __expf(e));
            o += y[n] * f * Cv[n];
        }
        out[r * DIN + d] = o + u * Dd;
    }
}

extern "C" void kernel_launch(void* const* d_in, const int* in_sizes, int n_in,
                              void* d_out, int out_size, void* d_ws, size_t ws_size,
                              hipStream_t stream) {
    const float* in   = (const float*)d_in[0];
    const float* Wdbc = (const float*)d_in[1];
    const float* g1   = (const float*)d_in[2];
    const float* b1   = (const float*)d_in[3];
    const float* Wdt  = (const float*)d_in[4];
    const float* bdt  = (const float*)d_in[5];
    const float* g2   = (const float*)d_in[6];
    const float* b2   = (const float*)d_in[7];
    const float* Alog = (const float*)d_in[8];
    const float* Dv   = (const float*)d_in[9];
    float* out = (float*)d_out;

    float* ws    = (float*)d_ws;
    float* dbc   = ws;                               // 16384*48      = 786,432
    float* delta = dbc   + (size_t)ROWS * DBCW;      // 16384*256     = 4,194,304
    float* Ebuf  = delta + (size_t)ROWS * DIN;       // 512*256*16    = 2,097,152
    float* Hbuf  = Ebuf  + (size_t)B_ * NC * 256 * 16;
    float* Tbuf  = Hbuf  + (size_t)B_ * NC * 256 * 16;  // 512*256    = 131,072
    float* Rbuf  = Tbuf  + (size_t)B_ * NC * 256;

    k_dbc  <<<dim3(ROWS / 8), dim3(128), 0, stream>>>(in, Wdbc, g1, b1, dbc);
    k_delta<<<dim3(ROWS),     dim3(256), 0, stream>>>(dbc, Wdt, bdt, g2, b2, delta);
    k_scanA<<<dim3(B_ * NC),  dim3(256), 0, stream>>>(delta, in, dbc, Alog, Ebuf, Tbuf);
    k_scanB<<<dim3(B_ * 4096 / 256), dim3(256), 0, stream>>>(Alog, Ebuf, Tbuf, Hbuf, Rbuf);
    k_scanC<<<dim3(B_ * NC),  dim3(256), 0, stream>>>(delta, in, dbc, Alog, Hbuf, Tbuf, Rbuf, Dv, out);
}